// Round 1
// baseline (147.365 us; speedup 1.0000x reference)
//
#include <hip/hip_runtime.h>

// Locally-connected conv (BioConvolution): per-patch GEMM
//   Z[n,p,o] = sum_k X_patch[n,p,k] * F[p,k,o],  k = i*128 + j*32 + c (K=512)
//   A = relu(Z + bias)
// N=32, H=W=128, FIN=FOUT=32, FH=FW=4, P=1024 (nr=nc=32).
// One block per patch p. 256 threads = 4 waves; each wave computes one 16x16
// output tile via v_mfma_f32_16x16x32_bf16, K processed in 2 halves of 256.

typedef __attribute__((ext_vector_type(4))) float f32x4;
typedef __attribute__((ext_vector_type(4))) short s16x4;
typedef __attribute__((ext_vector_type(8))) short s16x8;

#define HWC   (128 * 128 * 32)   // per-batch X stride (floats)
#define WC    (128 * 32)         // per-row X stride (floats)
#define KTOT  512
#define FOUT  32
// LDS row strides in shorts (bf16). Padding (+4 shorts = 8B) makes the
// stride 1032B/520B -> 258/130 dwords -> bank offset 2 per row ->
// ds_read_b64 fragment reads are conflict-free (4 accesses/bank = floor).
#define XROW  516   // 512 k + 4 pad  (1032 B per row, 32 rows = 33024 B)
#define FROW  260   // 256 k + 4 pad  ( 520 B per row, 32 rows = 16640 B)

__device__ __forceinline__ short f2bf(float f) {
    // round-to-nearest-even fp32 -> bf16
    unsigned u = __builtin_bit_cast(unsigned, f);
    u += 0x7fffu + ((u >> 16) & 1u);
    return (short)(u >> 16);
}

__launch_bounds__(256)
__global__ void lcconv_kernel(const float* __restrict__ X,
                              const float* __restrict__ F,
                              const float* __restrict__ bias,
                              float* __restrict__ out) {
    __shared__ short Xs[32 * XROW];   // X patch, bf16: [n][k]
    __shared__ short Fs[32 * FROW];   // filter half, bf16 TRANSPOSED: [o][k_local]

    const int p    = blockIdx.x;      // patch index, row-major (pr, pc)
    const int pr   = p >> 5;
    const int pc   = p & 31;
    const int tid  = threadIdx.x;
    const int lane = tid & 63;
    const int w    = tid >> 6;        // wave id 0..3
    const int mi   = (w >> 1) * 16;   // n-tile base
    const int ni   = (w & 1) * 16;    // o-tile base

    // ---------------- stage X patch: fp32 -> bf16 into Xs[n][k] ----------------
    {
        const int xbase = pr * 4 * WC + pc * (4 * 32);  // (pr*4, pc*4, c=0)
        #pragma unroll 4
        for (int it = 0; it < 16; ++it) {
            int idx = it * 256 + tid;        // float4 index in [0, 4096)
            int n   = idx >> 7;              // 128 float4 per n
            int r   = idx & 127;
            int i   = r >> 5;                // patch row 0..3
            int w4  = r & 31;                // float4 within 128-float segment
            const float* gp = X + n * HWC + xbase + i * WC + w4 * 4;
            f32x4 v = *(const f32x4*)gp;
            s16x4 b;
            b[0] = f2bf(v[0]); b[1] = f2bf(v[1]); b[2] = f2bf(v[2]); b[3] = f2bf(v[3]);
            int k = i * 128 + w4 * 4;
            *(s16x4*)(&Xs[n * XROW + k]) = b;
        }
    }

    f32x4 acc = {0.f, 0.f, 0.f, 0.f};
    const int arow = mi + (lane & 15);       // n row for A fragment
    const int brow = ni + (lane & 15);       // o row for B fragment
    const int g16  = (lane >> 4) * 8;        // k sub-offset within 32-step

    const float* Fp = F + p * (KTOT * FOUT);

    #pragma unroll
    for (int h = 0; h < 2; ++h) {
        // ---- stage filter half (k in [h*256, h*256+256)), transposed ----
        #pragma unroll
        for (int it = 0; it < 2; ++it) {
            int task = it * 256 + tid;       // [0, 512)
            int o4   = task & 7;             // float4 group of o
            int k4   = task >> 3;            // [0, 64): group of 4 k's
            const float* fp0 = Fp + (h * 256 + k4 * 4) * FOUT + o4 * 4;
            f32x4 d0 = *(const f32x4*)(fp0 + 0 * FOUT);
            f32x4 d1 = *(const f32x4*)(fp0 + 1 * FOUT);
            f32x4 d2 = *(const f32x4*)(fp0 + 2 * FOUT);
            f32x4 d3 = *(const f32x4*)(fp0 + 3 * FOUT);
            #pragma unroll
            for (int e = 0; e < 4; ++e) {
                s16x4 b;
                b[0] = f2bf(d0[e]); b[1] = f2bf(d1[e]);
                b[2] = f2bf(d2[e]); b[3] = f2bf(d3[e]);
                *(s16x4*)(&Fs[(o4 * 4 + e) * FROW + k4 * 4]) = b;
            }
        }
        __syncthreads();

        // ---- 8 MFMA k-steps over this half ----
        #pragma unroll
        for (int ks = 0; ks < 8; ++ks) {
            const short* ap = &Xs[arow * XROW + h * 256 + ks * 32 + g16];
            const short* bp = &Fs[brow * FROW + ks * 32 + g16];
            s16x4 alo = *(const s16x4*)(ap);
            s16x4 ahi = *(const s16x4*)(ap + 4);
            s16x4 blo = *(const s16x4*)(bp);
            s16x4 bhi = *(const s16x4*)(bp + 4);
            s16x8 a, b;
            a[0] = alo[0]; a[1] = alo[1]; a[2] = alo[2]; a[3] = alo[3];
            a[4] = ahi[0]; a[5] = ahi[1]; a[6] = ahi[2]; a[7] = ahi[3];
            b[0] = blo[0]; b[1] = blo[1]; b[2] = blo[2]; b[3] = blo[3];
            b[4] = bhi[0]; b[5] = bhi[1]; b[6] = bhi[2]; b[7] = bhi[3];
            acc = __builtin_amdgcn_mfma_f32_16x16x32_bf16(a, b, acc, 0, 0, 0);
        }
        __syncthreads();   // safe to overwrite Fs next half
    }

    // ---------------- epilogue: bias + ReLU, store fp32 ----------------
    // C/D layout (m89): col = lane&15 (o), row = (lane>>4)*4 + reg (n)
    const int o_g = ni + (lane & 15);
    const float bv = bias[o_g];
    #pragma unroll
    for (int r = 0; r < 4; ++r) {
        int n_g = mi + (lane >> 4) * 4 + r;
        float v = acc[r] + bv;
        v = v > 0.f ? v : 0.f;
        out[n_g * (1024 * FOUT) + p * FOUT + o_g] = v;
    }
}

extern "C" void kernel_launch(void* const* d_in, const int* in_sizes, int n_in,
                              void* d_out, int out_size, void* d_ws, size_t ws_size,
                              hipStream_t stream) {
    const float* X    = (const float*)d_in[0];
    const float* F    = (const float*)d_in[1];
    const float* bias = (const float*)d_in[2];
    float* out        = (float*)d_out;
    lcconv_kernel<<<dim3(1024), dim3(256), 0, stream>>>(X, F, bias, out);
}